// Round 5
// baseline (184.900 us; speedup 1.0000x reference)
//
#include <hip/hip_runtime.h>

// DTCWT level=3 on (8,512,512,3) f32 -> (8,1024,1024,3) f32.
// Three fused kernels (one per level).
// L0 (new this round): raw input tile staged in LDS once (coalesced float4,
//   no tap redundancy), 10-tap row filter runs from LDS -> swizzled inter LDS,
//   col filter + dual-tree combine from inter. Cuts global-load instructions
//   2.5x and removes the per-thread 10-deep in-flight load chain (VGPR down).
// L1/L2: stage A row-filters with float4 global loads (4 z planes),
//   register-transpose into XOR-swizzled LDS; stage B z-PAIR split: the
//   dual-tree combine couples only pairs {0,3},{1,2}; lower half-block does
//   {0,3}, upper half {1,2} -> all threads active, 24 accs/thread.
// Plain __launch_bounds__(NT): forcing min-waves (,5) caused VGPR=48 + 640 MB
//   scratch spill (round 3). Never force below natural allocation.
// afb: out[i] = sum_t f[t] * x[(2i+5-t) mod N]
// Tile(m,n) at rows [m*512,+512), cols [n*512,+512) of out; tile-local:
// lowpass 64x64 at (0,0); level-j bands (H=256,128,64): LH (0,H), HL (H,0), HH (H,H).

#define FF 0.08838834764832f
#define GG 0.01122679215254f
#define HHc 0.69587998903400f
#define AAc 0.03516384f
#define BBc 0.08832942f
#define CCc 0.23389032f
#define DDc 0.76027237f
#define EEc 0.58751830f
#define KKc 0.11430184f

// [bank: 0=Faf, 1=af][tree m][lo/hi][tap]
__device__ __constant__ float c_filt[2][2][2][10] = {
  { // Faf (first stage)
    { {0.f,-FF, FF, HHc, HHc, FF,-FF, GG, GG, 0.f},
      {0.f,-GG, GG, FF, FF,-HHc, HHc,-FF,-FF, 0.f} },
    { {GG, GG,-FF, FF, HHc, HHc, FF,-FF, 0.f, 0.f},
      {0.f, 0.f,-FF,-FF, HHc,-HHc, FF, FF, GG,-GG} }
  },
  { // af (q-shift, levels >= 1)
    { {AAc, 0.f,-BBc, CCc, DDc, EEc, 0.f,-KKc, 0.f, 0.f},
      {0.f, 0.f,-KKc, 0.f, EEc,-DDc, CCc, BBc, 0.f,-AAc} },
    { {0.f, 0.f,-KKc, 0.f, EEc, DDc, CCc,-BBc, 0.f, AAc},
      {-AAc, 0.f, BBc, CCc,-DDc, EEc, 0.f,-KKc, 0.f, 0.f} }
  }
};

__device__ __forceinline__ void cmb(float& a, float& b) {
  const float k = 0.70710678118654752440f;
  const float s = (a + b) * k, d = (a - b) * k;
  a = s; b = d;
}

// Injective bank swizzle on float4 indices: permutes low 3 bits (bank group)
// as a function of bits >=3. Range-preserving within 8-aligned octets.
__device__ __forceinline__ int swz4(int f4) { return f4 ^ ((f4 >> 3) & 7); }

// ---------------- L0: raw-LDS staged version ----------------
template<int N, int Ho, int Wo, int NT>
__global__ __launch_bounds__(NT) void fused_level0(
    const float* __restrict__ src,
    float* __restrict__ llout,
    float* __restrict__ out)
{
  constexpr int half = N / 2;
  constexpr int W2 = 2 * Wo + 8;               // col halo span (f4 units... in floats: 3*W2)
  constexpr int ROWF = 3 * N;                  // floats per image row
  constexpr int FL = 3 * W2;                   // flat floats per LDS row (216)
  constexpr int I4 = FL / 4;                   // float4s per LDS row (54)
  constexpr int RR = 2 * Ho + 8;               // raw rows incl. halo (16)
  constexpr int SIF4 = 3 * W2 + 4;             // inter il-stride in float4 (NF=4)
  constexpr size_t ZOUT = (size_t)8 * half * half * 3;
  static_assert(Ho * Wo * 2 == NT, "stage-B thread map (z-pair split)");
  __shared__ __align__(16) float raw[RR * FL];        // 16*216*4 = 13824 B
  __shared__ __align__(16) float inter[Ho * SIF4 * 4]; // 4*220*16 = 14080 B

  const int jt = blockIdx.x, it = blockIdx.y, b = blockIdx.z;
  const int i0 = it * Ho, j0 = jt * Wo;
  const int tid = threadIdx.x;

  int base = (2 * j0 - 4) * 3;                 // multiple of 4 floats (16B)
  if (base < 0) base += ROWF;

  // ---- Stage 0: global -> raw LDS, coalesced, no redundancy ----
  const float* sb = src + (size_t)b * N * ROWF;
  for (int item = tid; item < RR * I4; item += NT) {
    const int lr = item / I4;
    const int q4 = (item - lr * I4) * 4;
    int fg = base + q4;
    if (fg >= ROWF) fg -= ROWF;                // never straddles a float4
    const int g = (2 * i0 - 4 + lr) & (N - 1); // circular row
    *(float4*)&raw[lr * FL + q4] = *(const float4*)(sb + (size_t)g * ROWF + fg);
  }
  __syncthreads();

  // ---- Stage A': 10-tap row filter from raw LDS -> swizzled inter LDS ----
  // out row il needs raw rows lr = 2*il + 9 - t, t=0..9 (all in [0,RR)).
  for (int item = tid; item < Ho * I4; item += NT) {
    const int il = item / I4;
    const int q4 = (item - il * I4) * 4;
    float acc[4][4];
#pragma unroll
    for (int f = 0; f < 4; ++f)
#pragma unroll
      for (int k = 0; k < 4; ++k) acc[f][k] = 0.f;
#pragma unroll
    for (int t = 0; t < 10; ++t) {
      const int lr = 2 * il + 9 - t;
      const float4 v = *(const float4*)&raw[lr * FL + q4];
#pragma unroll
      for (int f = 0; f < 4; ++f) {
        const float fc = c_filt[0][f >> 1][f & 1][t];
        acc[f][0] += fc * v.x; acc[f][1] += fc * v.y;
        acc[f][2] += fc * v.z; acc[f][3] += fc * v.w;
      }
    }
#pragma unroll
    for (int f = 0; f < 4; ++f)
#pragma unroll
      for (int k = 0; k < 4; ++k) acc[f][k] *= 0.5f;  // x/2 folded
#pragma unroll
    for (int k = 0; k < 4; ++k) {
      const int fq = q4 + k;
      float4 w = make_float4(acc[0][k], acc[1][k], acc[2][k], acc[3][k]);
      *(float4*)&inter[(il * SIF4 + swz4(fq)) * 4] = w;
    }
  }
  __syncthreads();

  // ---- Stage B: col filter + combine, z-pair split (verified round 4) ----
  {
    const int pr = (tid >= Ho * Wo) ? 1 : 0;
    const int t7 = tid - pr * Ho * Wo;
    const int il = t7 / Wo, jl = t7 - (t7 / Wo) * Wo;
    const int za = pr, zb = 3 - pr;
    float LLa[3] = {}, LHa[3] = {}, HLa[3] = {}, HHa[3] = {};
    float LLb[3] = {}, LHb[3] = {}, HLb[3] = {}, HHb[3] = {};
#pragma unroll
    for (int s = 0; s < 10; ++s) {
      const int wl = 2 * jl + 9 - s;
      const float fla = c_filt[0][pr][0][s],     fha = c_filt[0][pr][1][s];
      const float flb = c_filt[0][1 - pr][0][s], fhb = c_filt[0][1 - pr][1][s];
#pragma unroll
      for (int c = 0; c < 3; ++c) {
        // v = {a0, d0, a1, d1}: za pairs m=0 data with col filter n=pr,
        // zb pairs m=1 data with col filter n=1-pr.
        const int f4 = wl * 3 + c;
        const float4 v = *(const float4*)&inter[(il * SIF4 + swz4(f4)) * 4];
        const float aa = v.x, da = v.y, ab = v.z, db = v.w;
        LLa[c] += fla * aa; LHa[c] += fha * aa;
        HLa[c] += fla * da; HHa[c] += fha * da;
        LLb[c] += flb * ab; LHb[c] += fhb * ab;
        HLb[c] += flb * db; HHb[c] += fhb * db;
      }
    }
#pragma unroll
    for (int c = 0; c < 3; ++c) {
      cmb(LHa[c], LHb[c]); cmb(HLa[c], HLb[c]); cmb(HHa[c], HHb[c]);
    }
    const int ig = i0 + il, jg = j0 + jl;
    const size_t outB = (size_t)b * (1024u * 1024u * 3u);
    {
      const int m = za >> 1, n = za & 1;
      const int r0 = m * 512, c0 = n * 512;
      float* pLL = llout + (size_t)za * ZOUT + (((size_t)b * half + ig) * half + jg) * 3;
      pLL[0] = LLa[0]; pLL[1] = LLa[1]; pLL[2] = LLa[2];
      float* pLH = out + outB + ((size_t)(r0 + ig) * 1024 + (c0 + half + jg)) * 3;
      pLH[0] = LHa[0]; pLH[1] = LHa[1]; pLH[2] = LHa[2];
      float* pHL = out + outB + ((size_t)(r0 + half + ig) * 1024 + (c0 + jg)) * 3;
      pHL[0] = HLa[0]; pHL[1] = HLa[1]; pHL[2] = HLa[2];
      float* pHH = out + outB + ((size_t)(r0 + half + ig) * 1024 + (c0 + half + jg)) * 3;
      pHH[0] = HHa[0]; pHH[1] = HHa[1]; pHH[2] = HHa[2];
    }
    {
      const int m = zb >> 1, n = zb & 1;
      const int r0 = m * 512, c0 = n * 512;
      float* pLL = llout + (size_t)zb * ZOUT + (((size_t)b * half + ig) * half + jg) * 3;
      pLL[0] = LLb[0]; pLL[1] = LLb[1]; pLL[2] = LLb[2];
      float* pLH = out + outB + ((size_t)(r0 + ig) * 1024 + (c0 + half + jg)) * 3;
      pLH[0] = LHb[0]; pLH[1] = LHb[1]; pLH[2] = LHb[2];
      float* pHL = out + outB + ((size_t)(r0 + half + ig) * 1024 + (c0 + jg)) * 3;
      pHL[0] = HLb[0]; pHL[1] = HLb[1]; pHL[2] = HLb[2];
      float* pHH = out + outB + ((size_t)(r0 + half + ig) * 1024 + (c0 + half + jg)) * 3;
      pHH[0] = HHb[0]; pHH[1] = HHb[1]; pHH[2] = HHb[2];
    }
  }
}

// ---------------- L1/L2: direct-load stage A + z-pair split stage B ----------------
template<int LVL, int N, int Ho, int Wo, int NT>
__global__ __launch_bounds__(NT) void fused_level(
    const float* __restrict__ src,
    float* __restrict__ llout,
    float* __restrict__ out)
{
  constexpr int half = N / 2;
  constexpr int W2 = 2 * Wo + 8;               // col halo span
  constexpr int NF = 8;                        // row-filter outputs per position
  constexpr int ROWF = 3 * N;                  // floats per image row
  constexpr int FL = 3 * W2;                   // flat floats per LDS row
  constexpr int SIF4 = (3 * W2 * NF) / 4 + 4;  // il-stride in float4 units
  constexpr size_t ZS = (size_t)8 * N * N * 3;
  constexpr size_t ZOUT = (size_t)8 * half * half * 3;
  static_assert(Ho * Wo * 2 == NT, "stage-B thread map (z-pair split)");
  __shared__ __align__(16) float inter[Ho * SIF4 * 4];

  const int jt = blockIdx.x, it = blockIdx.y, b = blockIdx.z;
  const int i0 = it * Ho, j0 = jt * Wo;
  const int tid = threadIdx.x;

  int base = (2 * j0 - 4) * 3;                 // multiple of 4 floats (16B)
  if (base < 0) base += ROWF;

  // ---- Stage A: row filter along H, float4 global loads -> swizzled LDS ----
  constexpr int I4 = FL / 4;
  for (int item = tid; item < Ho * I4; item += NT) {
    const int il = item / I4;
    const int q4 = (item - il * I4) * 4;       // flat local (w*3+c), mult of 4
    int fg = base + q4;
    if (fg >= ROWF) fg -= ROWF;                // never straddles a float4
    const int ig = i0 + il;
    float acc[NF][4];
#pragma unroll
    for (int f = 0; f < NF; ++f)
#pragma unroll
      for (int k = 0; k < 4; ++k) acc[f][k] = 0.f;

#pragma unroll
    for (int z = 0; z < 4; ++z) {
      const int m = z >> 1;
      const float* sp = src + (size_t)z * ZS + (size_t)b * N * ROWF + fg;
#pragma unroll
      for (int t = 0; t < 10; ++t) {
        const int r = (2 * ig + 5 - t) & (N - 1);
        const float4 v = *(const float4*)(sp + (size_t)r * ROWF);
        const float fl = c_filt[1][m][0][t], fh = c_filt[1][m][1][t];
        acc[2 * z][0] += fl * v.x; acc[2 * z][1] += fl * v.y;
        acc[2 * z][2] += fl * v.z; acc[2 * z][3] += fl * v.w;
        acc[2 * z + 1][0] += fh * v.x; acc[2 * z + 1][1] += fh * v.y;
        acc[2 * z + 1][2] += fh * v.z; acc[2 * z + 1][3] += fh * v.w;
      }
    }
    // transpose-write: per flat position fq, 8 filters as two float4s.
#pragma unroll
    for (int k = 0; k < 4; ++k) {
      const int fq = q4 + k;
      float4 w0 = make_float4(acc[0][k], acc[1][k], acc[2][k], acc[3][k]);
      float4 w1 = make_float4(acc[4][k], acc[5][k], acc[6][k], acc[7][k]);
      *(float4*)&inter[(il * SIF4 + swz4(2 * fq)) * 4] = w0;
      *(float4*)&inter[(il * SIF4 + swz4(2 * fq + 1)) * 4] = w1;
    }
  }
  __syncthreads();

  // ---- Stage B: col filter, combine, stores; z-pair split ----
  {
    const int pr = (tid >= Ho * Wo) ? 1 : 0;
    const int t7 = tid - pr * Ho * Wo;
    const int il = t7 / Wo, jl = t7 - (t7 / Wo) * Wo;
    const int za = pr, zb = 3 - pr;
    float LLa[3] = {}, LHa[3] = {}, HLa[3] = {}, HHa[3] = {};
    float LLb[3] = {}, LHb[3] = {}, HLb[3] = {}, HHb[3] = {};
#pragma unroll
    for (int s = 0; s < 10; ++s) {
      const int wl = 2 * jl + 9 - s;
      const float fla = c_filt[1][pr][0][s],     fha = c_filt[1][pr][1][s];
      const float flb = c_filt[1][1 - pr][0][s], fhb = c_filt[1][1 - pr][1][s];
#pragma unroll
      for (int c = 0; c < 3; ++c) {
        // v0 = {z0lo, z0hi, z1lo, z1hi}, v1 = {z2lo, z2hi, z3lo, z3hi}
        const int f4 = (wl * 3 + c) * 2;
        const float4 v0 = *(const float4*)&inter[(il * SIF4 + swz4(f4)) * 4];
        const float4 v1 = *(const float4*)&inter[(il * SIF4 + swz4(f4 + 1)) * 4];
        const float aa = pr ? v0.z : v0.x, da = pr ? v0.w : v0.y;  // za in {0,1}
        const float ab = pr ? v1.x : v1.z, db = pr ? v1.y : v1.w;  // zb in {3,2}
        LLa[c] += fla * aa; LHa[c] += fha * aa;
        HLa[c] += fla * da; HHa[c] += fha * da;
        LLb[c] += flb * ab; LHb[c] += fhb * ab;
        HLb[c] += flb * db; HHb[c] += fhb * db;
      }
    }
#pragma unroll
    for (int c = 0; c < 3; ++c) {
      cmb(LHa[c], LHb[c]); cmb(HLa[c], HLb[c]); cmb(HHa[c], HHb[c]);
    }
    const int ig = i0 + il, jg = j0 + jl;
    const size_t outB = (size_t)b * (1024u * 1024u * 3u);
    {
      const int m = za >> 1, n = za & 1;
      const int r0 = m * 512, c0 = n * 512;
      float* pLL;
      if constexpr (LVL == 2)
        pLL = out + outB + ((size_t)(r0 + ig) * 1024 + (c0 + jg)) * 3;
      else
        pLL = llout + (size_t)za * ZOUT + (((size_t)b * half + ig) * half + jg) * 3;
      pLL[0] = LLa[0]; pLL[1] = LLa[1]; pLL[2] = LLa[2];
      float* pLH = out + outB + ((size_t)(r0 + ig) * 1024 + (c0 + half + jg)) * 3;
      pLH[0] = LHa[0]; pLH[1] = LHa[1]; pLH[2] = LHa[2];
      float* pHL = out + outB + ((size_t)(r0 + half + ig) * 1024 + (c0 + jg)) * 3;
      pHL[0] = HLa[0]; pHL[1] = HLa[1]; pHL[2] = HLa[2];
      float* pHH = out + outB + ((size_t)(r0 + half + ig) * 1024 + (c0 + half + jg)) * 3;
      pHH[0] = HHa[0]; pHH[1] = HHa[1]; pHH[2] = HHa[2];
    }
    {
      const int m = zb >> 1, n = zb & 1;
      const int r0 = m * 512, c0 = n * 512;
      float* pLL;
      if constexpr (LVL == 2)
        pLL = out + outB + ((size_t)(r0 + ig) * 1024 + (c0 + jg)) * 3;
      else
        pLL = llout + (size_t)zb * ZOUT + (((size_t)b * half + ig) * half + jg) * 3;
      pLL[0] = LLb[0]; pLL[1] = LLb[1]; pLL[2] = LLb[2];
      float* pLH = out + outB + ((size_t)(r0 + ig) * 1024 + (c0 + half + jg)) * 3;
      pLH[0] = LHb[0]; pLH[1] = LHb[1]; pLH[2] = LHb[2];
      float* pHL = out + outB + ((size_t)(r0 + half + ig) * 1024 + (c0 + jg)) * 3;
      pHL[0] = HLb[0]; pHL[1] = HLb[1]; pHL[2] = HLb[2];
      float* pHH = out + outB + ((size_t)(r0 + half + ig) * 1024 + (c0 + half + jg)) * 3;
      pHH[0] = HHb[0]; pHH[1] = HHb[1]; pHH[2] = HHb[2];
    }
  }
}

extern "C" void kernel_launch(void* const* d_in, const int* in_sizes, int n_in,
                              void* d_out, int out_size, void* d_ws, size_t ws_size,
                              hipStream_t stream) {
  (void)in_sizes; (void)n_in; (void)out_size; (void)ws_size;
  const float* x = (const float*)d_in[0];
  float* out = (float*)d_out;
  float* LL1 = (float*)d_ws;        // 4*8*256*256*3 = 6,291,456 floats
  float* LL2 = LL1 + 6291456;       // 4*8*128*128*3 = 1,572,864 floats

  // L0: 512->256. Raw-staged, tile 4x32, LDS 13824+14080 = 27904 B, 4096 blocks.
  fused_level0<512, 4, 32, 256><<<dim3(8, 64, 8), 256, 0, stream>>>(x, LL1, out);
  // L1: 256->128. Tile 8x16, LDS 8*244*16 = 31232 B, 1024 blocks.
  fused_level<1, 256, 8, 16, 256><<<dim3(8, 16, 8), 256, 0, stream>>>(LL1, LL2, out);
  // L2: 128->64. Tile 8x16, LDS 31232 B, 256 blocks.
  fused_level<2, 128, 8, 16, 256><<<dim3(4, 8, 8), 256, 0, stream>>>(LL2, nullptr, out);
}

// Round 6
// 171.118 us; speedup vs baseline: 1.0805x; 1.0805x over previous
//
#include <hip/hip_runtime.h>

// DTCWT level=3 on (8,512,512,3) f32 -> (8,1024,1024,3) f32.
// Three kernels. L1/L2: EXACT round-0 baseline (verified 165us structure).
// L0 (this round): 2-tile pipelined kernel. Raw input rows are staged into
// double-buffered LDS via __builtin_amdgcn_global_load_lds (async DMA, no
// VGPR round-trip, no per-item vmcnt wait -> all staging loads of a tile
// in flight at once). Tile k+1's DMA is issued BEFORE tile k's compute, so
// HBM latency hides under the row/col filter VALU work; only the prologue
// load is latency-exposed. Row-filter-from-raw and z-split stage B are
// byte-identical to the round-5 harness-verified L0 math.
// afb: out[i] = sum_t f[t] * x[(2i+5-t) mod N]
// Tile(m,n) at rows [m*512,+512), cols [n*512,+512) of out; tile-local:
// lowpass 64x64 at (0,0); level-j bands (H=256,128,64): LH (0,H), HL (H,0), HH (H,H).

#define FF 0.08838834764832f
#define GG 0.01122679215254f
#define HHc 0.69587998903400f
#define AAc 0.03516384f
#define BBc 0.08832942f
#define CCc 0.23389032f
#define DDc 0.76027237f
#define EEc 0.58751830f
#define KKc 0.11430184f

// [bank: 0=Faf, 1=af][tree m][lo/hi][tap]
__device__ __constant__ float c_filt[2][2][2][10] = {
  { // Faf (first stage)
    { {0.f,-FF, FF, HHc, HHc, FF,-FF, GG, GG, 0.f},
      {0.f,-GG, GG, FF, FF,-HHc, HHc,-FF,-FF, 0.f} },
    { {GG, GG,-FF, FF, HHc, HHc, FF,-FF, 0.f, 0.f},
      {0.f, 0.f,-FF,-FF, HHc,-HHc, FF, FF, GG,-GG} }
  },
  { // af (q-shift, levels >= 1)
    { {AAc, 0.f,-BBc, CCc, DDc, EEc, 0.f,-KKc, 0.f, 0.f},
      {0.f, 0.f,-KKc, 0.f, EEc,-DDc, CCc, BBc, 0.f,-AAc} },
    { {0.f, 0.f,-KKc, 0.f, EEc, DDc, CCc,-BBc, 0.f, AAc},
      {-AAc, 0.f, BBc, CCc,-DDc, EEc, 0.f,-KKc, 0.f, 0.f} }
  }
};

__device__ __forceinline__ void cmb(float& a, float& b) {
  const float k = 0.70710678118654752440f;
  const float s = (a + b) * k, d = (a - b) * k;
  a = s; b = d;
}

// Injective bank swizzle on float4 indices: permutes low 3 bits (bank group)
// as a function of bits >=3. Range-preserving within 8-aligned octets.
__device__ __forceinline__ int swz4(int f4) { return f4 ^ ((f4 >> 3) & 7); }

#if defined(__has_builtin)
#if __has_builtin(__builtin_amdgcn_global_load_lds)
#define G2L_ASYNC 1
#endif
#endif

// 16-B global -> LDS copy. Async DMA when available (per-lane dest pointer:
// HW uses first-active-lane base + lane*16, which equals our linear mapping).
__device__ __forceinline__ void g2l16(const float* g, float* l) {
#ifdef G2L_ASYNC
  typedef const __attribute__((address_space(1))) float gfl;
  typedef __attribute__((address_space(3))) float lfl;
  __builtin_amdgcn_global_load_lds((gfl*)g, (lfl*)l, 16, 0, 0);
#else
  *(float4*)l = *(const float4*)g;
#endif
}

// ---------------- L0: 2-tile pipelined, DMA-staged ----------------
// Issue the raw-tile loads for output rows [i0, i0+Ho).
template<int N, int Ho, int Wo, int NT>
__device__ __forceinline__ void l0_issue(const float* sb, int i0, int base,
                                         float* rawbuf, int tid) {
  constexpr int ROWF = 3 * N;
  constexpr int W2 = 2 * Wo + 8;
  constexpr int FL = 3 * W2;
  constexpr int I4 = FL / 4;
  constexpr int RR = 2 * Ho + 8;
  for (int item = tid; item < RR * I4; item += NT) {
    const int lr = item / I4;
    const int q4 = (item - lr * I4) * 4;
    int fg = base + q4;
    if (fg >= ROWF) fg -= ROWF;                // never straddles a float4
    const int g = (2 * i0 - 4 + lr) & (N - 1); // circular row
    g2l16(sb + (size_t)g * ROWF + fg, rawbuf + (size_t)item * 4);
  }
}

// 10-tap row filter from raw LDS -> swizzled inter LDS (round-5 verified).
template<int N, int Ho, int Wo, int NT>
__device__ __forceinline__ void l0_rowfilt(const float* raw, float* inter,
                                           int tid) {
  constexpr int W2 = 2 * Wo + 8;
  constexpr int FL = 3 * W2;
  constexpr int I4 = FL / 4;
  constexpr int SIF4 = 3 * W2 + 4;
  for (int item = tid; item < Ho * I4; item += NT) {
    const int il = item / I4;
    const int q4 = (item - il * I4) * 4;
    float acc[4][4];
#pragma unroll
    for (int f = 0; f < 4; ++f)
#pragma unroll
      for (int k = 0; k < 4; ++k) acc[f][k] = 0.f;
#pragma unroll
    for (int t = 0; t < 10; ++t) {
      const int lr = 2 * il + 9 - t;
      const float4 v = *(const float4*)&raw[lr * FL + q4];
#pragma unroll
      for (int f = 0; f < 4; ++f) {
        const float fc = c_filt[0][f >> 1][f & 1][t];
        acc[f][0] += fc * v.x; acc[f][1] += fc * v.y;
        acc[f][2] += fc * v.z; acc[f][3] += fc * v.w;
      }
    }
#pragma unroll
    for (int f = 0; f < 4; ++f)
#pragma unroll
      for (int k = 0; k < 4; ++k) acc[f][k] *= 0.5f;  // x/2 folded
#pragma unroll
    for (int k = 0; k < 4; ++k) {
      const int fq = q4 + k;
      float4 w = make_float4(acc[0][k], acc[1][k], acc[2][k], acc[3][k]);
      *(float4*)&inter[(il * SIF4 + swz4(fq)) * 4] = w;
    }
  }
}

// Col filter + dual-tree combine + stores, z-pair split (round-5 verified).
template<int N, int Ho, int Wo, int NT>
__device__ __forceinline__ void l0_colfilt(const float* inter, int i0, int j0,
                                           int b, int tid,
                                           float* __restrict__ llout,
                                           float* __restrict__ out) {
  constexpr int half = N / 2;
  constexpr int W2 = 2 * Wo + 8;
  constexpr int SIF4 = 3 * W2 + 4;
  constexpr size_t ZOUT = (size_t)8 * half * half * 3;
  const int pr = (tid >= Ho * Wo) ? 1 : 0;
  const int t7 = tid - pr * Ho * Wo;
  const int il = t7 / Wo, jl = t7 - (t7 / Wo) * Wo;
  const int za = pr, zb = 3 - pr;
  float LLa[3] = {}, LHa[3] = {}, HLa[3] = {}, HHa[3] = {};
  float LLb[3] = {}, LHb[3] = {}, HLb[3] = {}, HHb[3] = {};
#pragma unroll
  for (int s = 0; s < 10; ++s) {
    const int wl = 2 * jl + 9 - s;
    const float fla = c_filt[0][pr][0][s],     fha = c_filt[0][pr][1][s];
    const float flb = c_filt[0][1 - pr][0][s], fhb = c_filt[0][1 - pr][1][s];
#pragma unroll
    for (int c = 0; c < 3; ++c) {
      // v = {a0, d0, a1, d1}: za pairs m=0 data with col filter n=pr,
      // zb pairs m=1 data with col filter n=1-pr.
      const int f4 = wl * 3 + c;
      const float4 v = *(const float4*)&inter[(il * SIF4 + swz4(f4)) * 4];
      const float aa = v.x, da = v.y, ab = v.z, db = v.w;
      LLa[c] += fla * aa; LHa[c] += fha * aa;
      HLa[c] += fla * da; HHa[c] += fha * da;
      LLb[c] += flb * ab; LHb[c] += fhb * ab;
      HLb[c] += flb * db; HHb[c] += fhb * db;
    }
  }
#pragma unroll
  for (int c = 0; c < 3; ++c) {
    cmb(LHa[c], LHb[c]); cmb(HLa[c], HLb[c]); cmb(HHa[c], HHb[c]);
  }
  const int ig = i0 + il, jg = j0 + jl;
  const size_t outB = (size_t)b * (1024u * 1024u * 3u);
  {
    const int m = za >> 1, n = za & 1;
    const int r0 = m * 512, c0 = n * 512;
    float* pLL = llout + (size_t)za * ZOUT + (((size_t)b * half + ig) * half + jg) * 3;
    pLL[0] = LLa[0]; pLL[1] = LLa[1]; pLL[2] = LLa[2];
    float* pLH = out + outB + ((size_t)(r0 + ig) * 1024 + (c0 + half + jg)) * 3;
    pLH[0] = LHa[0]; pLH[1] = LHa[1]; pLH[2] = LHa[2];
    float* pHL = out + outB + ((size_t)(r0 + half + ig) * 1024 + (c0 + jg)) * 3;
    pHL[0] = HLa[0]; pHL[1] = HLa[1]; pHL[2] = HLa[2];
    float* pHH = out + outB + ((size_t)(r0 + half + ig) * 1024 + (c0 + half + jg)) * 3;
    pHH[0] = HHa[0]; pHH[1] = HHa[1]; pHH[2] = HHa[2];
  }
  {
    const int m = zb >> 1, n = zb & 1;
    const int r0 = m * 512, c0 = n * 512;
    float* pLL = llout + (size_t)zb * ZOUT + (((size_t)b * half + ig) * half + jg) * 3;
    pLL[0] = LLb[0]; pLL[1] = LLb[1]; pLL[2] = LLb[2];
    float* pLH = out + outB + ((size_t)(r0 + ig) * 1024 + (c0 + half + jg)) * 3;
    pLH[0] = LHb[0]; pLH[1] = LHb[1]; pLH[2] = LHb[2];
    float* pHL = out + outB + ((size_t)(r0 + half + ig) * 1024 + (c0 + jg)) * 3;
    pHL[0] = HLb[0]; pHL[1] = HLb[1]; pHL[2] = HLb[2];
    float* pHH = out + outB + ((size_t)(r0 + half + ig) * 1024 + (c0 + half + jg)) * 3;
    pHH[0] = HHb[0]; pHH[1] = HHb[1]; pHH[2] = HHb[2];
  }
}

template<int N, int Ho, int Wo, int NT>
__global__ __launch_bounds__(NT) void fused_level0_pipe(
    const float* __restrict__ src,
    float* __restrict__ llout,
    float* __restrict__ out)
{
  constexpr int W2 = 2 * Wo + 8;
  constexpr int ROWF = 3 * N;
  constexpr int FL = 3 * W2;
  constexpr int RR = 2 * Ho + 8;
  constexpr int SIF4 = 3 * W2 + 4;
  static_assert(Ho * Wo * 2 == NT, "stage-B thread map (z-pair split)");
  __shared__ __align__(16) float raw0[RR * FL];        // 13824 B
  __shared__ __align__(16) float raw1[RR * FL];        // 13824 B
  __shared__ __align__(16) float inter[Ho * SIF4 * 4]; // 14080 B

  const int jt = blockIdx.x, ity = blockIdx.y, b = blockIdx.z;
  const int j0 = jt * Wo;
  const int i0a = (2 * ity) * Ho;                      // tile 0 rows
  const int i0b = i0a + Ho;                            // tile 1 rows
  const int tid = threadIdx.x;
  int base = (2 * j0 - 4) * 3;                         // multiple of 4 floats
  if (base < 0) base += ROWF;
  const float* sb = src + (size_t)b * N * ROWF;

  // prologue: tile-0 raw DMA (only latency-exposed load of the block)
  l0_issue<N, Ho, Wo, NT>(sb, i0a, base, raw0, tid);
  __syncthreads();                                     // drains DMA + barrier
  // tile-1 DMA flies under tile-0 compute
  l0_issue<N, Ho, Wo, NT>(sb, i0b, base, raw1, tid);
#ifdef G2L_ASYNC
  __builtin_amdgcn_sched_barrier(0);                   // keep issue ahead of compute
#endif
  l0_rowfilt<N, Ho, Wo, NT>(raw0, inter, tid);
  __syncthreads();
  l0_colfilt<N, Ho, Wo, NT>(inter, i0a, j0, b, tid, llout, out);
  __syncthreads();                                     // inter reads done; raw1 ready
  l0_rowfilt<N, Ho, Wo, NT>(raw1, inter, tid);
  __syncthreads();
  l0_colfilt<N, Ho, Wo, NT>(inter, i0b, j0, b, tid, llout, out);
}

// ---------------- L1/L2: EXACT round-0 baseline ----------------
template<int LVL, int N, int Ho, int Wo>
__global__ __launch_bounds__(256) void fused_level(
    const float* __restrict__ src,
    float* __restrict__ llout,
    float* __restrict__ out)
{
  constexpr int half = N / 2;
  constexpr int W2 = 2 * Wo + 8;               // col halo span
  constexpr int NF = (LVL == 0) ? 4 : 8;       // row-filter outputs per position
  constexpr int ROWF = 3 * N;                  // floats per image row
  constexpr int FL = 3 * W2;                   // flat floats per LDS row
  constexpr int SIF4 = (3 * W2 * NF) / 4 + 4;  // il-stride in float4 units
  constexpr size_t ZS = (size_t)8 * N * N * 3;
  constexpr size_t ZOUT = (size_t)8 * half * half * 3;
  __shared__ __align__(16) float inter[Ho * SIF4 * 4];

  const int jt = blockIdx.x, it = blockIdx.y, b = blockIdx.z;
  const int i0 = it * Ho, j0 = jt * Wo;
  const int tid = threadIdx.x;

  int base = (2 * j0 - 4) * 3;                 // multiple of 4 floats (16B)
  if (base < 0) base += ROWF;

  // ---- Stage A: row filter along H, float4 global loads -> swizzled LDS ----
  constexpr int I4 = FL / 4;
  for (int item = tid; item < Ho * I4; item += 256) {
    const int il = item / I4;
    const int q4 = (item - il * I4) * 4;       // flat local (w*3+c), mult of 4
    int fg = base + q4;
    if (fg >= ROWF) fg -= ROWF;                // never straddles a float4
    const int ig = i0 + il;
    float acc[NF][4];
#pragma unroll
    for (int f = 0; f < NF; ++f)
#pragma unroll
      for (int k = 0; k < 4; ++k) acc[f][k] = 0.f;

#pragma unroll
    for (int z = 0; z < 4; ++z) {
      const int m = z >> 1;
      const float* sp = src + (size_t)z * ZS + (size_t)b * N * ROWF + fg;
#pragma unroll
      for (int t = 0; t < 10; ++t) {
        const int r = (2 * ig + 5 - t) & (N - 1);
        const float4 v = *(const float4*)(sp + (size_t)r * ROWF);
        const float fl = c_filt[1][m][0][t], fh = c_filt[1][m][1][t];
        acc[2 * z][0] += fl * v.x; acc[2 * z][1] += fl * v.y;
        acc[2 * z][2] += fl * v.z; acc[2 * z][3] += fl * v.w;
        acc[2 * z + 1][0] += fh * v.x; acc[2 * z + 1][1] += fh * v.y;
        acc[2 * z + 1][2] += fh * v.z; acc[2 * z + 1][3] += fh * v.w;
      }
    }
    // transpose-write: per flat position fq, 8 filters as two float4s.
#pragma unroll
    for (int k = 0; k < 4; ++k) {
      const int fq = q4 + k;
      float4 w0 = make_float4(acc[0][k], acc[1][k], acc[2][k], acc[3][k]);
      float4 w1 = make_float4(acc[4][k], acc[5][k], acc[6][k], acc[7][k]);
      *(float4*)&inter[(il * SIF4 + swz4(2 * fq)) * 4] = w0;
      *(float4*)&inter[(il * SIF4 + swz4(2 * fq + 1)) * 4] = w1;
    }
  }
  __syncthreads();

  // ---- Stage B: col filter along W from LDS, combine, contiguous stores ----
  if (tid < Ho * Wo) {
    const int il = tid / Wo, jl = tid - (tid / Wo) * Wo;
    float LL[4][3] = {}, LH[4][3] = {}, HL[4][3] = {}, HH[4][3] = {};
#pragma unroll
    for (int s = 0; s < 10; ++s) {
      const int wl = 2 * jl + 9 - s;
#pragma unroll
      for (int c = 0; c < 3; ++c) {
        const int f4 = (wl * 3 + c) * 2;
        const float4 v0 = *(const float4*)&inter[(il * SIF4 + swz4(f4)) * 4];
        const float4 v1 = *(const float4*)&inter[(il * SIF4 + swz4(f4 + 1)) * 4];
        const float az[4] = {v0.x, v0.z, v1.x, v1.z};
        const float dz[4] = {v0.y, v0.w, v1.y, v1.w};
#pragma unroll
        for (int z = 0; z < 4; ++z) {
          const int n = z & 1;
          const float fl = c_filt[1][n][0][s], fh = c_filt[1][n][1][s];
          LL[z][c] += fl * az[z]; LH[z][c] += fh * az[z];
          HL[z][c] += fl * dz[z]; HH[z][c] += fh * dz[z];
        }
      }
    }
#pragma unroll
    for (int c = 0; c < 3; ++c) {
      cmb(LH[0][c], LH[3][c]); cmb(LH[1][c], LH[2][c]);
      cmb(HL[0][c], HL[3][c]); cmb(HL[1][c], HL[2][c]);
      cmb(HH[0][c], HH[3][c]); cmb(HH[1][c], HH[2][c]);
    }
    const int ig = i0 + il, jg = j0 + jl;
    const size_t outB = (size_t)b * (1024u * 1024u * 3u);
#pragma unroll
    for (int z = 0; z < 4; ++z) {
      const int m = z >> 1, n = z & 1;
      const int r0 = m * 512, c0 = n * 512;
      float* pLL;
      if constexpr (LVL == 2)
        pLL = out + outB + ((size_t)(r0 + ig) * 1024 + (c0 + jg)) * 3;
      else
        pLL = llout + (size_t)z * ZOUT + (((size_t)b * half + ig) * half + jg) * 3;
      pLL[0] = LL[z][0]; pLL[1] = LL[z][1]; pLL[2] = LL[z][2];
      float* pLH = out + outB + ((size_t)(r0 + ig) * 1024 + (c0 + half + jg)) * 3;
      pLH[0] = LH[z][0]; pLH[1] = LH[z][1]; pLH[2] = LH[z][2];
      float* pHL = out + outB + ((size_t)(r0 + half + ig) * 1024 + (c0 + jg)) * 3;
      pHL[0] = HL[z][0]; pHL[1] = HL[z][1]; pHL[2] = HL[z][2];
      float* pHH = out + outB + ((size_t)(r0 + half + ig) * 1024 + (c0 + half + jg)) * 3;
      pHH[0] = HH[z][0]; pHH[1] = HH[z][1]; pHH[2] = HH[z][2];
    }
  }
}

extern "C" void kernel_launch(void* const* d_in, const int* in_sizes, int n_in,
                              void* d_out, int out_size, void* d_ws, size_t ws_size,
                              hipStream_t stream) {
  (void)in_sizes; (void)n_in; (void)out_size; (void)ws_size;
  const float* x = (const float*)d_in[0];
  float* out = (float*)d_out;
  float* LL1 = (float*)d_ws;        // 4*8*256*256*3 = 6,291,456 floats
  float* LL2 = LL1 + 6291456;       // 4*8*128*128*3 = 1,572,864 floats

  // L0: 512->256. 2-tile pipelined blocks (Ho=4 each, paired along rows),
  // LDS 2*13824 + 14080 = 41728 B -> 3 blocks/CU. 2048 blocks.
  fused_level0_pipe<512, 4, 32, 256><<<dim3(8, 32, 8), 256, 0, stream>>>(x, LL1, out);
  // L1: 256->128. Tile 8x16, LDS 8*244*16 = 31232 B (round-0 baseline).
  fused_level<1, 256, 8, 16><<<dim3(8, 16, 8), 256, 0, stream>>>(LL1, LL2, out);
  // L2: 128->64. Tile 8x16 (round-0 baseline).
  fused_level<2, 128, 8, 16><<<dim3(4, 8, 8), 256, 0, stream>>>(LL2, nullptr, out);
}

// Round 7
// 170.699 us; speedup vs baseline: 1.0832x; 1.0025x over previous
//
#include <hip/hip_runtime.h>

// DTCWT level=3 on (8,512,512,3) f32 -> (8,1024,1024,3) f32.
// Three fused kernels (one per level). L0: EXACT round-0 baseline.
// L1/L2 (this round): stage A split across z-plane PAIRS — each item is
// computed by two threads (planes {0,1} -> inter slot 2fq, planes {2,3} ->
// slot 2fq+1), halving per-thread accumulators (16 vs 32) and in-flight
// loads (20 vs 40) so the allocator can land below the 102-VGPR occupancy
// step naturally (round 3: never FORCE occupancy via launch_bounds).
// Stage B for L1/L2 is the round-4-verified z-pair split (all 256 threads).
// afb: out[i] = sum_t f[t] * x[(2i+5-t) mod N]
// Tile(m,n) at rows [m*512,+512), cols [n*512,+512) of out; tile-local:
// lowpass 64x64 at (0,0); level-j bands (H=256,128,64): LH (0,H), HL (H,0), HH (H,H).

#define FF 0.08838834764832f
#define GG 0.01122679215254f
#define HHc 0.69587998903400f
#define AAc 0.03516384f
#define BBc 0.08832942f
#define CCc 0.23389032f
#define DDc 0.76027237f
#define EEc 0.58751830f
#define KKc 0.11430184f

// [bank: 0=Faf, 1=af][tree m][lo/hi][tap]
__device__ __constant__ float c_filt[2][2][2][10] = {
  { // Faf (first stage)
    { {0.f,-FF, FF, HHc, HHc, FF,-FF, GG, GG, 0.f},
      {0.f,-GG, GG, FF, FF,-HHc, HHc,-FF,-FF, 0.f} },
    { {GG, GG,-FF, FF, HHc, HHc, FF,-FF, 0.f, 0.f},
      {0.f, 0.f,-FF,-FF, HHc,-HHc, FF, FF, GG,-GG} }
  },
  { // af (q-shift, levels >= 1)
    { {AAc, 0.f,-BBc, CCc, DDc, EEc, 0.f,-KKc, 0.f, 0.f},
      {0.f, 0.f,-KKc, 0.f, EEc,-DDc, CCc, BBc, 0.f,-AAc} },
    { {0.f, 0.f,-KKc, 0.f, EEc, DDc, CCc,-BBc, 0.f, AAc},
      {-AAc, 0.f, BBc, CCc,-DDc, EEc, 0.f,-KKc, 0.f, 0.f} }
  }
};

__device__ __forceinline__ void cmb(float& a, float& b) {
  const float k = 0.70710678118654752440f;
  const float s = (a + b) * k, d = (a - b) * k;
  a = s; b = d;
}

// Injective bank swizzle on float4 indices: permutes low 3 bits (bank group)
// as a function of bits >=3. Range-preserving within 8-aligned octets.
__device__ __forceinline__ int swz4(int f4) { return f4 ^ ((f4 >> 3) & 7); }

// ---------------- L0: EXACT round-0 baseline ----------------
template<int N, int Ho, int Wo>
__global__ __launch_bounds__(256) void fused_level0(
    const float* __restrict__ src,
    float* __restrict__ llout,
    float* __restrict__ out)
{
  constexpr int half = N / 2;
  constexpr int W2 = 2 * Wo + 8;               // col halo span
  constexpr int ROWF = 3 * N;                  // floats per image row
  constexpr int FL = 3 * W2;                   // flat floats per LDS row
  constexpr int SIF4 = 3 * W2 + 4;             // il-stride in float4 units
  constexpr size_t ZOUT = (size_t)8 * half * half * 3;
  __shared__ __align__(16) float inter[Ho * SIF4 * 4];

  const int jt = blockIdx.x, it = blockIdx.y, b = blockIdx.z;
  const int i0 = it * Ho, j0 = jt * Wo;
  const int tid = threadIdx.x;

  int base = (2 * j0 - 4) * 3;                 // multiple of 4 floats (16B)
  if (base < 0) base += ROWF;

  // ---- Stage A: row filter along H, float4 global loads -> swizzled LDS ----
  constexpr int I4 = FL / 4;
  for (int item = tid; item < Ho * I4; item += 256) {
    const int il = item / I4;
    const int q4 = (item - il * I4) * 4;       // flat local (w*3+c), mult of 4
    int fg = base + q4;
    if (fg >= ROWF) fg -= ROWF;                // never straddles a float4
    const int ig = i0 + il;
    float acc[4][4];
#pragma unroll
    for (int f = 0; f < 4; ++f)
#pragma unroll
      for (int k = 0; k < 4; ++k) acc[f][k] = 0.f;

    const float* sp = src + (size_t)b * N * ROWF + fg;
#pragma unroll
    for (int t = 0; t < 10; ++t) {
      const int r = (2 * ig + 5 - t) & (N - 1);
      const float4 v = *(const float4*)(sp + (size_t)r * ROWF);
#pragma unroll
      for (int f = 0; f < 4; ++f) {
        const float fc = c_filt[0][f >> 1][f & 1][t];
        acc[f][0] += fc * v.x; acc[f][1] += fc * v.y;
        acc[f][2] += fc * v.z; acc[f][3] += fc * v.w;
      }
    }
#pragma unroll
    for (int f = 0; f < 4; ++f)
#pragma unroll
      for (int k = 0; k < 4; ++k) acc[f][k] *= 0.5f;  // x/2 folded
#pragma unroll
    for (int k = 0; k < 4; ++k) {
      const int fq = q4 + k;
      float4 w = make_float4(acc[0][k], acc[1][k], acc[2][k], acc[3][k]);
      *(float4*)&inter[(il * SIF4 + swz4(fq)) * 4] = w;
    }
  }
  __syncthreads();

  // ---- Stage B: col filter along W from LDS, combine, contiguous stores ----
  if (tid < Ho * Wo) {
    const int il = tid / Wo, jl = tid - (tid / Wo) * Wo;
    float LL[4][3] = {}, LH[4][3] = {}, HL[4][3] = {}, HH[4][3] = {};
#pragma unroll
    for (int s = 0; s < 10; ++s) {
      const int wl = 2 * jl + 9 - s;
#pragma unroll
      for (int c = 0; c < 3; ++c) {
        const int f4 = wl * 3 + c;
        const float4 v = *(const float4*)&inter[(il * SIF4 + swz4(f4)) * 4];
        const float a0 = v.x, d0 = v.y, a1 = v.z, d1 = v.w;
#pragma unroll
        for (int n = 0; n < 2; ++n) {
          const float fl = c_filt[0][n][0][s], fh = c_filt[0][n][1][s];
          LL[n][c] += fl * a0; LH[n][c] += fh * a0;
          HL[n][c] += fl * d0; HH[n][c] += fh * d0;
          LL[2 + n][c] += fl * a1; LH[2 + n][c] += fh * a1;
          HL[2 + n][c] += fl * d1; HH[2 + n][c] += fh * d1;
        }
      }
    }
#pragma unroll
    for (int c = 0; c < 3; ++c) {
      cmb(LH[0][c], LH[3][c]); cmb(LH[1][c], LH[2][c]);
      cmb(HL[0][c], HL[3][c]); cmb(HL[1][c], HL[2][c]);
      cmb(HH[0][c], HH[3][c]); cmb(HH[1][c], HH[2][c]);
    }
    const int ig = i0 + il, jg = j0 + jl;
    const size_t outB = (size_t)b * (1024u * 1024u * 3u);
#pragma unroll
    for (int z = 0; z < 4; ++z) {
      const int m = z >> 1, n = z & 1;
      const int r0 = m * 512, c0 = n * 512;
      float* pLL = llout + (size_t)z * ZOUT + (((size_t)b * half + ig) * half + jg) * 3;
      pLL[0] = LL[z][0]; pLL[1] = LL[z][1]; pLL[2] = LL[z][2];
      float* pLH = out + outB + ((size_t)(r0 + ig) * 1024 + (c0 + half + jg)) * 3;
      pLH[0] = LH[z][0]; pLH[1] = LH[z][1]; pLH[2] = LH[z][2];
      float* pHL = out + outB + ((size_t)(r0 + half + ig) * 1024 + (c0 + jg)) * 3;
      pHL[0] = HL[z][0]; pHL[1] = HL[z][1]; pHL[2] = HL[z][2];
      float* pHH = out + outB + ((size_t)(r0 + half + ig) * 1024 + (c0 + half + jg)) * 3;
      pHH[0] = HH[z][0]; pHH[1] = HH[z][1]; pHH[2] = HH[z][2];
    }
  }
}

// ---------------- L1/L2: split-z stage A + z-pair-split stage B ----------------
template<int LVL, int N, int Ho, int Wo, int NT>
__global__ __launch_bounds__(NT) void fused_level(
    const float* __restrict__ src,
    float* __restrict__ llout,
    float* __restrict__ out)
{
  constexpr int half = N / 2;
  constexpr int W2 = 2 * Wo + 8;               // col halo span
  constexpr int ROWF = 3 * N;                  // floats per image row
  constexpr int FL = 3 * W2;                   // flat floats per LDS row
  constexpr int SIF4 = (3 * W2 * 8) / 4 + 4;   // il-stride in float4 units
  constexpr size_t ZS = (size_t)8 * N * N * 3;
  constexpr size_t ZOUT = (size_t)8 * half * half * 3;
  static_assert(Ho * Wo * 2 == NT, "stage-B thread map (z-pair split)");
  __shared__ __align__(16) float inter[Ho * SIF4 * 4];

  const int jt = blockIdx.x, it = blockIdx.y, b = blockIdx.z;
  const int i0 = it * Ho, j0 = jt * Wo;
  const int tid = threadIdx.x;

  int base = (2 * j0 - 4) * 3;                 // multiple of 4 floats (16B)
  if (base < 0) base += ROWF;

  // ---- Stage A: row filter, SPLIT across z-plane pairs ----
  // Item space doubled: items [0, Ho*I4) handle planes {0,1} -> slot 2fq,
  // items [Ho*I4, 2*Ho*I4) handle planes {2,3} -> slot 2fq+1.
  // Halves per-thread acc (16 regs) and in-flight loads (20).
  constexpr int I4 = FL / 4;
  for (int item = tid; item < 2 * Ho * I4; item += NT) {
    const int zi = (item >= Ho * I4) ? 1 : 0;
    const int rest = item - zi * Ho * I4;
    const int il = rest / I4;
    const int q4 = (rest - il * I4) * 4;       // flat local (w*3+c), mult of 4
    int fg = base + q4;
    if (fg >= ROWF) fg -= ROWF;                // never straddles a float4
    const int ig = i0 + il;
    float acc[4][4];
#pragma unroll
    for (int f = 0; f < 4; ++f)
#pragma unroll
      for (int k = 0; k < 4; ++k) acc[f][k] = 0.f;

#pragma unroll
    for (int zz = 0; zz < 2; ++zz) {
      const int z = 2 * zi + zz;
      // m = z>>1 == zi for both zz (planes {0,1}->m0? NO: z=0,1 -> m=0; z=2,3 -> m=1)
      const float* sp = src + (size_t)z * ZS + (size_t)b * N * ROWF + fg;
      const float* fz = c_filt[1][zi][0];      // m == zi; [0]=lo row, +10 = hi row
#pragma unroll
      for (int t = 0; t < 10; ++t) {
        const int r = (2 * ig + 5 - t) & (N - 1);
        const float4 v = *(const float4*)(sp + (size_t)r * ROWF);
        const float fl = fz[t], fh = fz[10 + t];
        acc[2 * zz][0] += fl * v.x; acc[2 * zz][1] += fl * v.y;
        acc[2 * zz][2] += fl * v.z; acc[2 * zz][3] += fl * v.w;
        acc[2 * zz + 1][0] += fh * v.x; acc[2 * zz + 1][1] += fh * v.y;
        acc[2 * zz + 1][2] += fh * v.z; acc[2 * zz + 1][3] += fh * v.w;
      }
    }
    // write: zi=0 -> slot 2fq (z0lo,z0hi,z1lo,z1hi); zi=1 -> 2fq+1 (z2..z3)
#pragma unroll
    for (int k = 0; k < 4; ++k) {
      const int fq = q4 + k;
      float4 w = make_float4(acc[0][k], acc[1][k], acc[2][k], acc[3][k]);
      *(float4*)&inter[(il * SIF4 + swz4(2 * fq + zi)) * 4] = w;
    }
  }
  __syncthreads();

  // ---- Stage B: col filter, combine, stores; z-pair split (round-4 verified) ----
  {
    const int pr = (tid >= Ho * Wo) ? 1 : 0;
    const int t7 = tid - pr * Ho * Wo;
    const int il = t7 / Wo, jl = t7 - (t7 / Wo) * Wo;
    const int za = pr, zb = 3 - pr;
    float LLa[3] = {}, LHa[3] = {}, HLa[3] = {}, HHa[3] = {};
    float LLb[3] = {}, LHb[3] = {}, HLb[3] = {}, HHb[3] = {};
#pragma unroll
    for (int s = 0; s < 10; ++s) {
      const int wl = 2 * jl + 9 - s;
      const float fla = c_filt[1][pr][0][s],     fha = c_filt[1][pr][1][s];
      const float flb = c_filt[1][1 - pr][0][s], fhb = c_filt[1][1 - pr][1][s];
#pragma unroll
      for (int c = 0; c < 3; ++c) {
        // v0 = {z0lo, z0hi, z1lo, z1hi}, v1 = {z2lo, z2hi, z3lo, z3hi}
        const int f4 = (wl * 3 + c) * 2;
        const float4 v0 = *(const float4*)&inter[(il * SIF4 + swz4(f4)) * 4];
        const float4 v1 = *(const float4*)&inter[(il * SIF4 + swz4(f4 + 1)) * 4];
        const float aa = pr ? v0.z : v0.x, da = pr ? v0.w : v0.y;  // za in {0,1}
        const float ab = pr ? v1.x : v1.z, db = pr ? v1.y : v1.w;  // zb in {3,2}
        LLa[c] += fla * aa; LHa[c] += fha * aa;
        HLa[c] += fla * da; HHa[c] += fha * da;
        LLb[c] += flb * ab; LHb[c] += fhb * ab;
        HLb[c] += flb * db; HHb[c] += fhb * db;
      }
    }
#pragma unroll
    for (int c = 0; c < 3; ++c) {
      cmb(LHa[c], LHb[c]); cmb(HLa[c], HLb[c]); cmb(HHa[c], HHb[c]);
    }
    const int ig = i0 + il, jg = j0 + jl;
    const size_t outB = (size_t)b * (1024u * 1024u * 3u);
    {
      const int m = za >> 1, n = za & 1;
      const int r0 = m * 512, c0 = n * 512;
      float* pLL;
      if constexpr (LVL == 2)
        pLL = out + outB + ((size_t)(r0 + ig) * 1024 + (c0 + jg)) * 3;
      else
        pLL = llout + (size_t)za * ZOUT + (((size_t)b * half + ig) * half + jg) * 3;
      pLL[0] = LLa[0]; pLL[1] = LLa[1]; pLL[2] = LLa[2];
      float* pLH = out + outB + ((size_t)(r0 + ig) * 1024 + (c0 + half + jg)) * 3;
      pLH[0] = LHa[0]; pLH[1] = LHa[1]; pLH[2] = LHa[2];
      float* pHL = out + outB + ((size_t)(r0 + half + ig) * 1024 + (c0 + jg)) * 3;
      pHL[0] = HLa[0]; pHL[1] = HLa[1]; pHL[2] = HLa[2];
      float* pHH = out + outB + ((size_t)(r0 + half + ig) * 1024 + (c0 + half + jg)) * 3;
      pHH[0] = HHa[0]; pHH[1] = HHa[1]; pHH[2] = HHa[2];
    }
    {
      const int m = zb >> 1, n = zb & 1;
      const int r0 = m * 512, c0 = n * 512;
      float* pLL;
      if constexpr (LVL == 2)
        pLL = out + outB + ((size_t)(r0 + ig) * 1024 + (c0 + jg)) * 3;
      else
        pLL = llout + (size_t)zb * ZOUT + (((size_t)b * half + ig) * half + jg) * 3;
      pLL[0] = LLb[0]; pLL[1] = LLb[1]; pLL[2] = LLb[2];
      float* pLH = out + outB + ((size_t)(r0 + ig) * 1024 + (c0 + half + jg)) * 3;
      pLH[0] = LHb[0]; pLH[1] = LHb[1]; pLH[2] = LHb[2];
      float* pHL = out + outB + ((size_t)(r0 + half + ig) * 1024 + (c0 + jg)) * 3;
      pHL[0] = HLb[0]; pHL[1] = HLb[1]; pHL[2] = HLb[2];
      float* pHH = out + outB + ((size_t)(r0 + half + ig) * 1024 + (c0 + half + jg)) * 3;
      pHH[0] = HHb[0]; pHH[1] = HHb[1]; pHH[2] = HHb[2];
    }
  }
}

extern "C" void kernel_launch(void* const* d_in, const int* in_sizes, int n_in,
                              void* d_out, int out_size, void* d_ws, size_t ws_size,
                              hipStream_t stream) {
  (void)in_sizes; (void)n_in; (void)out_size; (void)ws_size;
  const float* x = (const float*)d_in[0];
  float* out = (float*)d_out;
  float* LL1 = (float*)d_ws;        // 4*8*256*256*3 = 6,291,456 floats
  float* LL2 = LL1 + 6291456;       // 4*8*128*128*3 = 1,572,864 floats

  // L0: 512->256. Round-0 baseline. Tile 8x32, LDS 8*220*16 = 28160 B.
  fused_level0<512, 8, 32><<<dim3(8, 32, 8), 256, 0, stream>>>(x, LL1, out);
  // L1: 256->128. Tile 8x16, LDS 8*244*16 = 31232 B, split-z stage A.
  fused_level<1, 256, 8, 16, 256><<<dim3(8, 16, 8), 256, 0, stream>>>(LL1, LL2, out);
  // L2: 128->64. Tile 8x16, split-z stage A.
  fused_level<2, 128, 8, 16, 256><<<dim3(4, 8, 8), 256, 0, stream>>>(LL2, nullptr, out);
}